// Round 8
// baseline (40.388 us; speedup 1.0000x reference)
//
#include <hip/hip_runtime.h>

#define NB 4
#define CH 256
#define CL 512
#define HH 64
#define HWD 64
#define LHD 32
#define LWD 32
#define PLANE (HH*HWD)      // 4096
#define LPLANE (LHD*LWD)    // 1024
#define NPIX (NB*PLANE)     // 16384
#define DPH 36              // padded pooled row stride (1 halo left, 3 right)
#define DROWS 34            // 32 + 1 halo each side
#define DPLANE (DROWS*DPH)  // 1224

// ------- Kernel 1: BN partial sums + raw 2x2 pool into halo-padded Dlowp -------
// Block = (b, c): 1024 blocks x 256 threads.
__global__ void stats_pool_kernel(const float* __restrict__ high,
                                  float* __restrict__ Dlowp,
                                  float* __restrict__ pS,
                                  float* __restrict__ pS2) {
    int bid = blockIdx.x;
    int c = bid & 255, b = bid >> 8;
    int tid = threadIdx.x;
    const float* hp = high + (((size_t)(b * CH + c)) << 12);
    float* dp = Dlowp + ((size_t)(b * CH + c)) * DPLANE;

    int xg = tid & 15;           // 16 x-groups of 4
    int rp0 = tid >> 4;          // row-pair base 0..15
    float s = 0.f, s2 = 0.f;
    #pragma unroll
    for (int i = 0; i < 2; ++i) {
        int rp = rp0 + 16 * i;   // 0..31
        const float* r0 = hp + (rp * 2) * HWD + xg * 4;
        float4 v0 = *(const float4*)r0;
        float4 v1 = *(const float4*)(r0 + HWD);
        s  += v0.x + v0.y + v0.z + v0.w + v1.x + v1.y + v1.z + v1.w;
        s2 += v0.x*v0.x + v0.y*v0.y + v0.z*v0.z + v0.w*v0.w
            + v1.x*v1.x + v1.y*v1.y + v1.z*v1.z + v1.w*v1.w;
        float p0 = 0.25f * (v0.x + v0.y + v1.x + v1.y);
        float p1 = 0.25f * (v0.z + v0.w + v1.z + v1.w);
        dp[(rp + 1) * DPH + 2 * xg + 1] = p0;
        dp[(rp + 1) * DPH + 2 * xg + 2] = p1;
    }
    // zero halo: rows 0/33 full, cols 0/33 of rows 1..32
    if (tid < DPH) { dp[tid] = 0.f; dp[33 * DPH + tid] = 0.f; }
    if (tid < 32)  { dp[(tid + 1) * DPH] = 0.f; dp[(tid + 1) * DPH + 33] = 0.f; }

    __shared__ float sm1[4], sm2[4];
    int lane = tid & 63, wid = tid >> 6;
    #pragma unroll
    for (int off = 32; off > 0; off >>= 1) {
        s  += __shfl_down(s, off);
        s2 += __shfl_down(s2, off);
    }
    if (lane == 0) { sm1[wid] = s; sm2[wid] = s2; }
    __syncthreads();
    if (tid == 0) {
        pS [c * 4 + b] = sm1[0] + sm1[1] + sm1[2] + sm1[3];
        pS2[c * 4 + b] = sm2[0] + sm2[1] + sm2[2] + sm2[3];
    }
}

// ------- Kernel 2: channel-major HSq + E[4] + DSq, 8-px strips -------
// Block = (b, y, xhalf): 512 blocks x 256 threads. chunk = tid>>2 (64 x 4ch), xi = tid&3 (8 px).
__global__ __launch_bounds__(256) void cE_kernel(const float* __restrict__ high,
                                                 const float* __restrict__ Dlowp,
                                                 const float* __restrict__ pS,
                                                 const float* __restrict__ pS2,
                                                 const float* __restrict__ gamma,
                                                 const float* __restrict__ beta,
                                                 float* __restrict__ HSq,
                                                 float* __restrict__ DSq,
                                                 float* __restrict__ E) {
    int bid = blockIdx.x;
    int xh = bid & 1;
    int y  = (bid >> 1) & 63;
    int b  = bid >> 7;
    int tid = threadIdx.x;

    __shared__ float sc_s[256], sh_s[256];
    __shared__ float red[64][33][5];     // padded: bank = (5*chunk + 8*xi)%32 -> 2-way max
    __shared__ float red2[64][17];

    if (tid < 256) {
        int c = tid;
        float4 s4 = *(const float4*)(pS + c * 4);
        float4 q4 = *(const float4*)(pS2 + c * 4);
        float S  = s4.x + s4.y + s4.z + s4.w;
        float S2 = q4.x + q4.y + q4.z + q4.w;
        const float invN = 1.f / (float)(NB * PLANE);
        float mean = S * invN;
        float var  = S2 * invN - mean * mean;
        float sc = gamma[c] * rsqrtf(var + 1e-5f);
        sc_s[c] = sc;
        sh_s[c] = beta[c] - mean * sc;
    }
    __syncthreads();

    int xi = tid & 3, chunk = tid >> 2;
    int c0 = chunk * 4;
    int lx0 = xh * 16 + xi * 4;      // low-x strip base
    int x0  = 2 * lx0;               // hi-x strip base (8 px)
    int ey0 = (y >> 1) - 1 + (y & 1);
    bool row0_oob = (y == 0);
    bool row1_oob = (y == 63);
    bool w0_oob = (lx0 == 0);
    bool w5_oob = (lx0 == 28);

    float a[8][5];
    #pragma unroll
    for (int m = 0; m < 8; ++m) {
        #pragma unroll
        for (int s = 0; s < 5; ++s) a[m][s] = 0.f;
    }
    float dsq[4] = {0.f, 0.f, 0.f, 0.f};

    #pragma unroll
    for (int j = 0; j < 4; ++j) {
        int c = c0 + j;
        float sc = sc_s[c], sh = sh_s[c];
        const float* hp = high + ((((size_t)(b * CH + c)) << 12) | (y << 6) | x0);
        float4 hv0 = *(const float4*)hp;
        float4 hv1 = *(const float4*)(hp + 4);
        float h[8] = { fmaf(hv0.x, sc, sh), fmaf(hv0.y, sc, sh),
                       fmaf(hv0.z, sc, sh), fmaf(hv0.w, sc, sh),
                       fmaf(hv1.x, sc, sh), fmaf(hv1.y, sc, sh),
                       fmaf(hv1.z, sc, sh), fmaf(hv1.w, sc, sh) };

        const float* dprow = Dlowp + ((size_t)(b * CH + c)) * DPLANE + (ey0 + 1) * DPH + lx0;
        float4 d0a = *(const float4*)(dprow);
        float4 d0b = *(const float4*)(dprow + 4);
        float4 d1a = *(const float4*)(dprow + DPH);
        float4 d1b = *(const float4*)(dprow + DPH + 4);
        float w0[6] = { fmaf(d0a.x, sc, sh), fmaf(d0a.y, sc, sh), fmaf(d0a.z, sc, sh),
                        fmaf(d0a.w, sc, sh), fmaf(d0b.x, sc, sh), fmaf(d0b.y, sc, sh) };
        float w1[6] = { fmaf(d1a.x, sc, sh), fmaf(d1a.y, sc, sh), fmaf(d1a.z, sc, sh),
                        fmaf(d1a.w, sc, sh), fmaf(d1b.x, sc, sh), fmaf(d1b.y, sc, sh) };
        if (row0_oob) {
            for (int t = 0; t < 6; ++t) w0[t] = 0.f;
        }
        if (row1_oob) {
            for (int t = 0; t < 6; ++t) w1[t] = 0.f;
        }
        if (w0_oob) { w0[0] = 0.f; w1[0] = 0.f; }
        if (w5_oob) { w0[5] = 0.f; w1[5] = 0.f; }

        #pragma unroll
        for (int m = 0; m < 8; ++m) {
            const int base = (m >> 1) + (m & 1);   // 0,1,1,2,2,3,3,4
            a[m][0] = fmaf(h[m], h[m],         a[m][0]);
            a[m][1] = fmaf(h[m], w0[base],     a[m][1]);   // sy0 sx0
            a[m][2] = fmaf(h[m], w0[base + 1], a[m][2]);   // sy0 sx1
            a[m][3] = fmaf(h[m], w1[base],     a[m][3]);   // sy1 sx0
            a[m][4] = fmaf(h[m], w1[base + 1], a[m][4]);   // sy1 sx1
        }
        // DSq row ly = y/2 is w1 when y even; local lx = lx0+t -> w1[t+1]
        #pragma unroll
        for (int t = 0; t < 4; ++t) dsq[t] = fmaf(w1[t + 1], w1[t + 1], dsq[t]);
    }

    #pragma unroll
    for (int m = 0; m < 8; ++m) {
        #pragma unroll
        for (int s = 0; s < 5; ++s) red[chunk][xi * 8 + m][s] = a[m][s];
    }
    #pragma unroll
    for (int t = 0; t < 4; ++t) red2[chunk][xi * 4 + t] = dsq[t];
    __syncthreads();

    if (tid < 160) {
        int r = tid >> 5, pxl = tid & 31;
        float s = 0.f;
        #pragma unroll
        for (int ch = 0; ch < 64; ++ch) s += red[ch][pxl][r];
        int pix = (b << 12) | (y << 6) | (xh * 32 + pxl);
        if (r == 0) HSq[pix] = s;
        else        E[(size_t)pix * 4 + (r - 1)] = -2.f * s;
    } else if (tid < 176 && (y & 1) == 0) {
        int pxl = tid - 160;
        float s = 0.f;
        #pragma unroll
        for (int ch = 0; ch < 64; ++ch) s += red2[ch][pxl];
        DSq[(b << 10) | ((y >> 1) << 5) | (xh * 16 + pxl)] = s;
    }
}

// ------- Kernel 3: score assembly + softmax -> att (once per pixel) -------
__global__ void att_kernel(const float* __restrict__ HSq,
                           const float* __restrict__ DSq,
                           const float* __restrict__ E,
                           const float* __restrict__ bias,
                           float* __restrict__ att) {
    int bid = blockIdx.x;        // 256: b*64 + y
    int y = bid & 63, b = bid >> 6;
    int x = threadIdx.x;         // 64
    int ly = y >> 1;

    float e[9];
    float m = -1e30f;
    #pragma unroll
    for (int k = 0; k < 9; ++k) {
        int dy = k / 3 - 1, dx = k % 3 - 1;
        int py = y + dy, px = x + dx;
        int qy = ly + dy, qx = (x >> 1) + dx;
        float s = 0.f;
        if (py >= 0 && py < HH && px >= 0 && px < HWD) {
            int pidx = (b << 12) | (py << 6) | px;
            int sy = (dy + 1 - (py & 1)) > 0;
            int sx = (dx + 1 - (px & 1)) > 0;
            s = HSq[pidx] + E[(size_t)pidx * 4 + sy * 2 + sx];
        }
        if (qy >= 0 && qy < LHD && qx >= 0 && qx < LWD)
            s += DSq[(b << 10) | (qy << 5) | qx];
        e[k] = s + bias[k];
        m = fmaxf(m, e[k]);
    }
    float sum = 0.f;
    #pragma unroll
    for (int k = 0; k < 9; ++k) { e[k] = __expf(e[k] - m); sum += e[k]; }
    float inv = 1.f / sum;
    float* ap = att + (size_t)b * 9 * PLANE + (y << 6) + x;
    #pragma unroll
    for (int k = 0; k < 9; ++k) ap[k * PLANE] = e[k] * inv;
}

// ------- Kernel 4: pure weighted aggregation -------
__global__ void out_kernel(const float* __restrict__ low,
                           const float* __restrict__ att,
                           float* __restrict__ out) {
    int bid = blockIdx.x;        // 1024: ((b*64)+y)*4 + lq
    int lq = bid & 3;
    int y  = (bid >> 2) & 63;
    int b  = bid >> 8;
    int tid = threadIdx.x;       // 256
    int ly = y >> 1;

    int xg = tid & 7;
    int lg = tid >> 3;           // 0..31
    int lx0 = xg * 4;
    int x0  = xg * 8;
    int l0  = lq * 128 + lg * 4;

    const float* ap = att + (size_t)b * 9 * PLANE + (y << 6) + x0;
    float a[9][8];
    #pragma unroll
    for (int k = 0; k < 9; ++k) {
        float4 v0 = *(const float4*)(ap + k * PLANE);
        float4 v1 = *(const float4*)(ap + k * PLANE + 4);
        a[k][0] = v0.x; a[k][1] = v0.y; a[k][2] = v0.z; a[k][3] = v0.w;
        a[k][4] = v1.x; a[k][5] = v1.y; a[k][6] = v1.z; a[k][7] = v1.w;
    }

    #pragma unroll
    for (int li = 0; li < 4; ++li) {
        const float* lp = low + (size_t)(b * CL + l0 + li) * LPLANE;
        float lv[3][6];
        #pragma unroll
        for (int dy = 0; dy < 3; ++dy) {
            int lyy = ly + dy - 1;
            if (lyy >= 0 && lyy < LHD) {
                const float* rp = lp + lyy * LWD;
                float4 mid = *(const float4*)(rp + lx0);
                lv[dy][1] = mid.x; lv[dy][2] = mid.y; lv[dy][3] = mid.z; lv[dy][4] = mid.w;
                lv[dy][0] = (lx0 > 0) ? rp[lx0 - 1] : 0.f;
                lv[dy][5] = (lx0 + 4 < LWD) ? rp[lx0 + 4] : 0.f;
            } else {
                #pragma unroll
                for (int j = 0; j < 6; ++j) lv[dy][j] = 0.f;
            }
        }
        float o[8];
        #pragma unroll
        for (int xi = 0; xi < 8; ++xi) {
            int base = xi >> 1;
            float s = 0.f;
            #pragma unroll
            for (int k = 0; k < 9; ++k) {
                int dy = k / 3, dx = k % 3;
                s += a[k][xi] * lv[dy][base + dx];
            }
            o[xi] = s;
        }
        float* op = out + (size_t)(b * CL + l0 + li) * PLANE + (y << 6) + x0;
        *(float4*)(op)     = make_float4(o[0], o[1], o[2], o[3]);
        *(float4*)(op + 4) = make_float4(o[4], o[5], o[6], o[7]);
    }
}

extern "C" void kernel_launch(void* const* d_in, const int* in_sizes, int n_in,
                              void* d_out, int out_size, void* d_ws, size_t ws_size,
                              hipStream_t stream) {
    const float* low   = (const float*)d_in[0];
    const float* high  = (const float*)d_in[1];
    const float* gamma = (const float*)d_in[2];
    const float* beta  = (const float*)d_in[3];
    const float* bias  = (const float*)d_in[4];
    float* out = (float*)d_out;

    float* ws = (float*)d_ws;
    float* pS    = ws;                                // 1024
    float* pS2   = pS + 1024;                         // 1024
    float* Dlowp = pS2 + 1024;                        // 4*256*1224 = 1253376
    float* HSq   = Dlowp + (size_t)NB * CH * DPLANE;  // 16384
    float* DSq   = HSq + NPIX;                        // 4096
    float* E     = DSq + NB * LPLANE;                 // 65536
    float* att   = E + (size_t)NPIX * 4;              // 147456

    stats_pool_kernel<<<1024, 256, 0, stream>>>(high, Dlowp, pS, pS2);
    cE_kernel<<<512, 256, 0, stream>>>(high, Dlowp, pS, pS2, gamma, beta, HSq, DSq, E);
    att_kernel<<<256, 64, 0, stream>>>(HSq, DSq, E, bias, att);
    out_kernel<<<1024, 256, 0, stream>>>(low, att, out);
}

// Round 9
// 33.718 us; speedup vs baseline: 1.1978x; 1.1978x over previous
//
#include <hip/hip_runtime.h>

#define NB 4
#define CH 256
#define CL 512
#define HH 64
#define HWD 64
#define LHD 32
#define LWD 32
#define PLANE (HH*HWD)      // 4096
#define LPLANE (LHD*LWD)    // 1024
#define NPIX (NB*PLANE)     // 16384
#define DPH 34              // padded pooled dims (1-halo)
#define DPLANE (DPH*DPH)    // 1156

// ------- Kernel 1: BN partial sums + raw 2x2 pool into halo-padded Dlowp -------
// Block = (b, c): 1024 blocks x 256 threads.
__global__ void stats_pool_kernel(const float* __restrict__ high,
                                  float* __restrict__ Dlowp,
                                  float* __restrict__ pS,
                                  float* __restrict__ pS2) {
    int bid = blockIdx.x;
    int c = bid & 255, b = bid >> 8;
    int tid = threadIdx.x;
    const float* hp = high + (((size_t)(b * CH + c)) << 12);
    float* dp = Dlowp + ((size_t)(b * CH + c)) * DPLANE;

    int xg = tid & 15;           // 16 x-groups of 4
    int rp0 = tid >> 4;          // row-pair base 0..15
    float s = 0.f, s2 = 0.f;
    #pragma unroll
    for (int i = 0; i < 2; ++i) {
        int rp = rp0 + 16 * i;   // 0..31
        const float* r0 = hp + (rp * 2) * HWD + xg * 4;
        float4 v0 = *(const float4*)r0;
        float4 v1 = *(const float4*)(r0 + HWD);
        s  += v0.x + v0.y + v0.z + v0.w + v1.x + v1.y + v1.z + v1.w;
        s2 += v0.x*v0.x + v0.y*v0.y + v0.z*v0.z + v0.w*v0.w
            + v1.x*v1.x + v1.y*v1.y + v1.z*v1.z + v1.w*v1.w;
        float p0 = 0.25f * (v0.x + v0.y + v1.x + v1.y);
        float p1 = 0.25f * (v0.z + v0.w + v1.z + v1.w);
        dp[(rp + 1) * DPH + 2 * xg + 1] = p0;
        dp[(rp + 1) * DPH + 2 * xg + 2] = p1;
    }
    // zero halo
    if (tid < DPH) { dp[tid] = 0.f; dp[33 * DPH + tid] = 0.f; }
    if (tid < 32)  { dp[(tid + 1) * DPH] = 0.f; dp[(tid + 1) * DPH + 33] = 0.f; }

    // block reduce
    __shared__ float sm1[4], sm2[4];
    int lane = tid & 63, wid = tid >> 6;
    #pragma unroll
    for (int off = 32; off > 0; off >>= 1) {
        s  += __shfl_down(s, off);
        s2 += __shfl_down(s2, off);
    }
    if (lane == 0) { sm1[wid] = s; sm2[wid] = s2; }
    __syncthreads();
    if (tid == 0) {
        pS [c * 4 + b] = sm1[0] + sm1[1] + sm1[2] + sm1[3];
        pS2[c * 4 + b] = sm2[0] + sm2[1] + sm2[2] + sm2[3];
    }
}

// ------- Kernel 2: channel-major HSq + E[4] + DSq -------
// Block = (b, y): 256 blocks x 512 threads. chunk = tid>>4 (32 chunks x 8 c), xi = tid&15 (4 x each).
__global__ __launch_bounds__(512) void cE_kernel(const float* __restrict__ high,
                                                 const float* __restrict__ Dlowp,
                                                 const float* __restrict__ pS,
                                                 const float* __restrict__ pS2,
                                                 const float* __restrict__ gamma,
                                                 const float* __restrict__ beta,
                                                 float* __restrict__ HSq,
                                                 float* __restrict__ DSq,
                                                 float* __restrict__ E) {
    int bid = blockIdx.x;
    int y = bid & 63, b = bid >> 6;
    int tid = threadIdx.x;

    __shared__ float sc_s[256], sh_s[256];
    __shared__ float red[32][65][5];     // padded: chunk stride 325 = 5 mod 32 -> 2-way max
    __shared__ float red2[32][33];

    if (tid < 256) {
        int c = tid;
        float4 s4 = *(const float4*)(pS + c * 4);
        float4 q4 = *(const float4*)(pS2 + c * 4);
        float S  = s4.x + s4.y + s4.z + s4.w;
        float S2 = q4.x + q4.y + q4.z + q4.w;
        const float invN = 1.f / (float)(NB * PLANE);
        float mean = S * invN;
        float var  = S2 * invN - mean * mean;
        float sc = gamma[c] * rsqrtf(var + 1e-5f);
        sc_s[c] = sc;
        sh_s[c] = beta[c] - mean * sc;
    }
    __syncthreads();

    int xi = tid & 15, chunk = tid >> 4;
    int x0 = xi * 4;
    int k = 2 * xi;
    int ey0 = (y >> 1) - 1 + (y & 1);
    bool row0_oob = (ey0 < 0);           // only y == 0
    bool row1_oob = (ey0 + 1 > 31);      // only y == 63
    bool col0_oob = (xi == 0);
    bool col3_oob = (xi == 15);

    float a[4][5];
    #pragma unroll
    for (int m = 0; m < 4; ++m) {
        #pragma unroll
        for (int s = 0; s < 5; ++s) a[m][s] = 0.f;
    }
    float dsq0 = 0.f, dsq1 = 0.f;

    #pragma unroll
    for (int j = 0; j < 8; ++j) {
        int c = chunk * 8 + j;
        float sc = sc_s[c], sh = sh_s[c];
        float4 hr = *(const float4*)(high + ((((size_t)(b * CH + c)) << 12) | (y << 6) | x0));
        float h0 = fmaf(hr.x, sc, sh);
        float h1 = fmaf(hr.y, sc, sh);
        float h2 = fmaf(hr.z, sc, sh);
        float h3 = fmaf(hr.w, sc, sh);

        const float* dp = Dlowp + ((size_t)(b * CH + c)) * DPLANE + (ey0 + 1) * DPH + k;
        float2 d0a = *(const float2*)(dp);
        float2 d0b = *(const float2*)(dp + 2);
        float2 d1a = *(const float2*)(dp + DPH);
        float2 d1b = *(const float2*)(dp + DPH + 2);
        float d0[4] = { fmaf(d0a.x, sc, sh), fmaf(d0a.y, sc, sh),
                        fmaf(d0b.x, sc, sh), fmaf(d0b.y, sc, sh) };
        float d1[4] = { fmaf(d1a.x, sc, sh), fmaf(d1a.y, sc, sh),
                        fmaf(d1b.x, sc, sh), fmaf(d1b.y, sc, sh) };
        if (row0_oob) { d0[0] = d0[1] = d0[2] = d0[3] = 0.f; }
        if (row1_oob) { d1[0] = d1[1] = d1[2] = d1[3] = 0.f; }
        if (col0_oob) { d0[0] = 0.f; d1[0] = 0.f; }
        if (col3_oob) { d0[3] = 0.f; d1[3] = 0.f; }

        float h[4] = { h0, h1, h2, h3 };
        #pragma unroll
        for (int m = 0; m < 4; ++m) {
            const int base = (m >> 1) + (m & 1);   // 0,1,1,2
            a[m][0] = fmaf(h[m], h[m],         a[m][0]);
            a[m][1] = fmaf(h[m], d0[base],     a[m][1]);   // sy0 sx0
            a[m][2] = fmaf(h[m], d0[base + 1], a[m][2]);   // sy0 sx1
            a[m][3] = fmaf(h[m], d1[base],     a[m][3]);   // sy1 sx0
            a[m][4] = fmaf(h[m], d1[base + 1], a[m][4]);   // sy1 sx1
        }
        // DSq row (ey = ly) is d1 when y even; cols local 1,2 = lx 2xi, 2xi+1
        dsq0 = fmaf(d1[1], d1[1], dsq0);
        dsq1 = fmaf(d1[2], d1[2], dsq1);
    }

    #pragma unroll
    for (int m = 0; m < 4; ++m) {
        #pragma unroll
        for (int s = 0; s < 5; ++s) red[chunk][x0 + m][s] = a[m][s];
    }
    red2[chunk][2 * xi]     = dsq0;
    red2[chunk][2 * xi + 1] = dsq1;
    __syncthreads();

    int px = tid & 63, r = tid >> 6;     // r = 0..7
    if (r < 5) {
        float s = 0.f;
        #pragma unroll
        for (int ch = 0; ch < 32; ++ch) s += red[ch][px][r];
        int pix = (b << 12) | (y << 6) | px;
        if (r == 0) HSq[pix] = s;
        else        E[(size_t)pix * 4 + (r - 1)] = -2.f * s;
    } else if (r == 5 && (y & 1) == 0 && px < 32) {
        float s = 0.f;
        #pragma unroll
        for (int ch = 0; ch < 32; ++ch) s += red2[ch][px];
        DSq[(b << 10) | ((y >> 1) << 5) | px] = s;
    }
}

// ------- Kernel 3: fused score-assembly + softmax (LDS) + weighted aggregation -------
__global__ void fused_out_kernel(const float* __restrict__ low,
                                 const float* __restrict__ HSq,
                                 const float* __restrict__ DSq,
                                 const float* __restrict__ E,
                                 const float* __restrict__ bias,
                                 float* __restrict__ out) {
    int bid = blockIdx.x;        // 1024: ((b*64)+y)*4 + lq
    int lq = bid & 3;
    int y  = (bid >> 2) & 63;
    int b  = bid >> 8;
    int tid = threadIdx.x;       // 256
    int ly = y >> 1;

    __shared__ float sc_lds[9][64];
    __shared__ float att_lds[9][64];

    for (int it = tid; it < 576; it += 256) {
        int x = it & 63;
        int k = it >> 6;         // 0..8
        int dy = k / 3 - 1, dx = k % 3 - 1;
        int py = y + dy, px = x + dx;
        int qy = ly + dy, qx = (x >> 1) + dx;
        float s = 0.f;
        if (py >= 0 && py < HH && px >= 0 && px < HWD) {
            int pidx = (b << 12) | (py << 6) | px;
            int sy = (dy + 1 - (py & 1)) > 0;
            int sx = (dx + 1 - (px & 1)) > 0;
            s = HSq[pidx] + E[(size_t)pidx * 4 + sy * 2 + sx];
        }
        if (qy >= 0 && qy < LHD && qx >= 0 && qx < LWD)
            s += DSq[(b << 10) | (qy << 5) | qx];
        sc_lds[k][x] = s + bias[k];
    }
    __syncthreads();

    if (tid < 64) {
        int x = tid;
        float e[9];
        float m = -1e30f;
        #pragma unroll
        for (int k = 0; k < 9; ++k) { e[k] = sc_lds[k][x]; m = fmaxf(m, e[k]); }
        float sum = 0.f;
        #pragma unroll
        for (int k = 0; k < 9; ++k) { e[k] = __expf(e[k] - m); sum += e[k]; }
        float inv = 1.f / sum;
        #pragma unroll
        for (int k = 0; k < 9; ++k) att_lds[k][x] = e[k] * inv;
    }
    __syncthreads();

    int xg = tid & 7;
    int lg = tid >> 3;           // 0..31
    int lx0 = xg * 4;
    int x0  = xg * 8;
    int l0  = lq * 128 + lg * 4;

    float a[9][8];
    #pragma unroll
    for (int k = 0; k < 9; ++k) {
        #pragma unroll
        for (int xi = 0; xi < 8; ++xi) a[k][xi] = att_lds[k][x0 + xi];
    }

    #pragma unroll
    for (int li = 0; li < 4; ++li) {
        const float* lp = low + (size_t)(b * CL + l0 + li) * LPLANE;
        float lv[3][6];
        #pragma unroll
        for (int dy = 0; dy < 3; ++dy) {
            int lyy = ly + dy - 1;
            if (lyy >= 0 && lyy < LHD) {
                const float* rp = lp + lyy * LWD;
                float4 mid = *(const float4*)(rp + lx0);
                lv[dy][1] = mid.x; lv[dy][2] = mid.y; lv[dy][3] = mid.z; lv[dy][4] = mid.w;
                lv[dy][0] = (lx0 > 0) ? rp[lx0 - 1] : 0.f;
                lv[dy][5] = (lx0 + 4 < LWD) ? rp[lx0 + 4] : 0.f;
            } else {
                #pragma unroll
                for (int j = 0; j < 6; ++j) lv[dy][j] = 0.f;
            }
        }
        float o[8];
        #pragma unroll
        for (int xi = 0; xi < 8; ++xi) {
            int base = xi >> 1;
            float s = 0.f;
            #pragma unroll
            for (int k = 0; k < 9; ++k) {
                int dy = k / 3, dx = k % 3;
                s += a[k][xi] * lv[dy][base + dx];
            }
            o[xi] = s;
        }
        float* op = out + (size_t)(b * CL + l0 + li) * PLANE + (y << 6) + x0;
        *(float4*)(op)     = make_float4(o[0], o[1], o[2], o[3]);
        *(float4*)(op + 4) = make_float4(o[4], o[5], o[6], o[7]);
    }
}

extern "C" void kernel_launch(void* const* d_in, const int* in_sizes, int n_in,
                              void* d_out, int out_size, void* d_ws, size_t ws_size,
                              hipStream_t stream) {
    const float* low   = (const float*)d_in[0];
    const float* high  = (const float*)d_in[1];
    const float* gamma = (const float*)d_in[2];
    const float* beta  = (const float*)d_in[3];
    const float* bias  = (const float*)d_in[4];
    float* out = (float*)d_out;

    float* ws = (float*)d_ws;
    float* pS    = ws;                                // 1024
    float* pS2   = pS + 1024;                         // 1024
    float* Dlowp = pS2 + 1024;                        // 4*256*1156 = 1183744
    float* HSq   = Dlowp + (size_t)NB * CH * DPLANE;  // 16384
    float* DSq   = HSq + NPIX;                        // 4096
    float* E     = DSq + NB * LPLANE;                 // 65536

    stats_pool_kernel<<<1024, 256, 0, stream>>>(high, Dlowp, pS, pS2);
    cE_kernel<<<256, 512, 0, stream>>>(high, Dlowp, pS, pS2, gamma, beta, HSq, DSq, E);
    fused_out_kernel<<<1024, 256, 0, stream>>>(low, HSq, DSq, E, bias, out);
}